// Round 12
// baseline (124.576 us; speedup 1.0000x reference)
//
#include <hip/hip_runtime.h>
#include <hip/hip_bf16.h>

#define BATCH 8
#define CIN 32
#define COUT 32
#define NK 4
#define HH 512
#define WW 512
#define HW (HH*WW)
#define EPSV 1e-8f

typedef __attribute__((ext_vector_type(8))) short short8;   // bf16 MFMA frag (4 VGPR)
typedef __attribute__((ext_vector_type(16))) float f32x16;  // 32x32 accumulator

static __device__ __forceinline__ unsigned short to_bf16(float f) {
    __hip_bfloat16 h = __float2bfloat16(f);
    return *reinterpret_cast<unsigned short*>(&h);
}

// ---------------------------------------------------------------------------
// Kernel 1: mixed+modulated+demodulated weights -> bf16 wt[b][oc][k], k=tap*32+ci
// ---------------------------------------------------------------------------
__global__ __launch_bounds__(320) void prep_weights(
    const float* __restrict__ mod,         // [B, CIN]
    const float* __restrict__ kernel_mod,  // [B, NK]
    const float* __restrict__ weights,     // [NK, COUT, CIN, 3, 3]
    unsigned short* __restrict__ wtb)      // [B, COUT, 288] bf16
{
    const int b  = blockIdx.x / COUT;
    const int oc = blockIdx.x % COUT;
    const int t  = threadIdx.x;            // 0..319, active < 288

    const float k0 = kernel_mod[b * NK + 0];
    const float k1 = kernel_mod[b * NK + 1];
    const float k2 = kernel_mod[b * NK + 2];
    const float k3 = kernel_mod[b * NK + 3];
    const float mx = fmaxf(fmaxf(k0, k1), fmaxf(k2, k3));
    const float e0 = expf(k0 - mx), e1 = expf(k1 - mx);
    const float e2 = expf(k2 - mx), e3 = expf(k3 - mx);
    const float inv_s = 1.0f / (e0 + e1 + e2 + e3);
    const float a0 = e0 * inv_s, a1 = e1 * inv_s, a2 = e2 * inv_s, a3 = e3 * inv_s;

    float w = 0.0f;
    int i = 0, tap = 0;
    if (t < CIN * 9) {
        i   = t / 9;
        tap = t % 9;
        const int base = (oc * CIN + i) * 9 + tap;
        const int nstride = COUT * CIN * 9;
        w = a0 * weights[base]
          + a1 * weights[base + nstride]
          + a2 * weights[base + 2 * nstride]
          + a3 * weights[base + 3 * nstride];
        w *= (mod[b * CIN + i] + 1.0f);
    }

    float s = w * w;
    #pragma unroll
    for (int off = 1; off < 64; off <<= 1) s += __shfl_xor(s, off);
    __shared__ float red[5];
    const int wid = t >> 6, lane = t & 63;
    if (lane == 0) red[wid] = s;
    __syncthreads();
    const float tot = red[0] + red[1] + red[2] + red[3] + red[4];
    const float inv_norm = rsqrtf(fmaxf(tot, EPSV));

    if (t < CIN * 9)
        wtb[(b * COUT + oc) * 288 + tap * CIN + i] = to_bf16(w * inv_norm);
}

// ---------------------------------------------------------------------------
// Kernel 2 (fused v6 = v2 + depth-2 pipelined staging, NO setprio).
// Block: 512 thr (8 waves), tile 16 rows x 32 px, one batch slice.
// Staging: lane-pair float4 loads (2x512B dense segments per instr), direct
// 2B scatter into interleaved LDS [chunk(8ci)][slot][16B], quad-local
// swizzle. DEPTH-2: decode+issue load k+1 before cvt+writes of k (named
// scalar rotation, no arrays -> no scratch). Halo loads issued FIRST,
// written last.
// Compute: wave w -> row-tiles (w, w+8); 18 x mfma_f32_32x32x16_bf16 each,
// D[m=oc][n=px]; epilogue scalar NT dword stores (2x128B/instr per wave).
// LEDGER (do not reintroduce): setprio around MFMA = 4x regression
// (r6/r7/r10: FETCH+WRITE inflate ~4x); reg-ARRAY batching = scratch spill
// (r6, rule #20); operand-swap epilogue = 32B store segments (+84MB
// partial-line writes, r9); stride-4-slot dword-merge swizzle = more
// conflicts (r6).
// ---------------------------------------------------------------------------
#define ROWS 16
#define XW 32
#define SR 18              // staged rows
#define SPR 37             // slots per row: 36 quad px + 1 left-halo
#define CH_STRIDE 668      // padded chunk stride (swizzle image <= 667)
#define QP 176             // padded quads per ci (162 real = 18 rows x 9)

static __device__ __forceinline__ int swz(int s) {
    return (s & ~3) | ((s ^ (s >> 2)) & 3);   // involution within quad groups
}

struct StageInfo {
    const float4* p;   // load address (nullptr = masked / zero-fill)
    int wr;            // write to LDS? (q < 162)
    int c;             // chunk 0..3
    int o;             // ushort lane within 16B slot
    int s0;            // base slot
};

__global__ __launch_bounds__(512, 6) void conv_fused(
    const float* __restrict__ fmap,           // [B, CIN, H, W] f32
    const unsigned short* __restrict__ wtb,   // [B, COUT, 288] bf16
    float* __restrict__ out)                  // [B, COUT, H, W] f32
{
    __shared__ short8 lds[4 * CH_STRIDE];     // 42,752 B -> 3 blocks/CU

    // XCD-pinned decomposition: XCD (n&7) owns batch b, sweeps tiles row-major
    const int n  = blockIdx.x;
    const int b  = n & 7;
    const int m  = n >> 3;
    const int x0 = (m & 15) * XW;             // 16 x-tiles
    const int y0 = (m >> 4) * ROWS;           // 32 y-tiles

    const int t    = threadIdx.x;
    const int lane = t & 63;
    const int w    = t >> 6;                  // wave 0..7
    const int oc   = lane & 31;
    const int half = lane >> 5;

    unsigned short* ldsu = (unsigned short*)lds;
    const float* fb = fmap + (size_t)b * CIN * HW;

    // ---- halo loads issued FIRST (longest-latency stragglers) ----
    float hv0 = 0.0f, hv1 = 0.0f;
    {
        const int ci = t & 31, r = t >> 5;    // r 0..15
        const int gy = y0 + r - 1;
        if (gy >= 0 && gy < HH && x0 > 0)
            hv0 = fb[(size_t)ci * HW + (size_t)gy * WW + (x0 - 1)];
    }
    if (t < 64) {
        const int ci = t & 31, r = 16 + (t >> 5);   // r 16,17
        const int gy = y0 + r - 1;
        if (gy >= 0 && gy < HH && x0 > 0)
            hv1 = fb[(size_t)ci * HW + (size_t)gy * WW + (x0 - 1)];
    }

    // ---- P1: depth-2 pipelined quad staging (32 ci x 162 quads) ----
    auto decode = [&](int k) {
        const int u  = t + 512 * k;           // < 5632 = 32*QP
        const int pr = u >> 1;                // lane-pair id
        const int cp = pr / QP;               // ci-pair 0..15
        const int q  = pr - cp * QP;          // 0..175
        const int ci = cp * 2 + (u & 1);
        StageInfo si;
        si.p  = nullptr;
        si.wr = (q < 162);
        si.c  = ci >> 3;
        si.o  = ci & 7;
        si.s0 = 0;
        if (si.wr) {
            const int r  = q / 9;             // 0..17
            const int qq = q - r * 9;         // 0..8
            const int gy = y0 + r - 1;
            const int gx = x0 + qq * 4;       // 16B-aligned (x0 % 32 == 0)
            si.s0 = r * SPR + qq * 4;
            if (gy >= 0 && gy < HH && gx + 3 < WW)
                si.p = reinterpret_cast<const float4*>(
                           fb + (size_t)ci * HW + (size_t)gy * WW + gx);
        }
        return si;
    };

    StageInfo siA = decode(0);
    float4 vA = make_float4(0.f, 0.f, 0.f, 0.f);
    if (siA.p) vA = *siA.p;

    #pragma unroll
    for (int k = 0; k < 11; ++k) {
        StageInfo siB;
        float4 vB = make_float4(0.f, 0.f, 0.f, 0.f);
        if (k + 1 < 11) {                     // issue NEXT load before writes
            siB = decode(k + 1);
            if (siB.p) vB = *siB.p;
        }
        if (siA.wr) {
            const int base = siA.c * CH_STRIDE;
            ldsu[(base + swz(siA.s0 + 0)) * 8 + siA.o] = to_bf16(vA.x);
            ldsu[(base + swz(siA.s0 + 1)) * 8 + siA.o] = to_bf16(vA.y);
            ldsu[(base + swz(siA.s0 + 2)) * 8 + siA.o] = to_bf16(vA.z);
            ldsu[(base + swz(siA.s0 + 3)) * 8 + siA.o] = to_bf16(vA.w);
        }
        if (k + 1 < 11) { siA = siB; vA = vB; }
    }

    // ---- halo writes (slot 36 per row) ----
    {
        const int ci = t & 31, r = t >> 5;
        ldsu[((ci >> 3) * CH_STRIDE + swz(r * SPR + 36)) * 8 + (ci & 7)] = to_bf16(hv0);
    }
    if (t < 64) {
        const int ci = t & 31, r = 16 + (t >> 5);
        ldsu[((ci >> 3) * CH_STRIDE + swz(r * SPR + 36)) * 8 + (ci & 7)] = to_bf16(hv1);
    }
    __syncthreads();

    // ---- compute: wave w -> row-tiles w and w+8 ----
    const unsigned short* wp = wtb + (size_t)(b * COUT + oc) * 288 + half * 8;
    const int col = oc;                       // output x within tile

    f32x16 acc0, acc1;
    #pragma unroll
    for (int reg = 0; reg < 16; ++reg) { acc0[reg] = 0.0f; acc1[reg] = 0.0f; }

    #pragma unroll
    for (int s = 0; s < 18; ++s) {
        const int tap = s >> 1;               // 0..8
        const int dy  = tap / 3;
        const int dx  = tap % 3;
        const int c   = ((s & 1) << 1) | half;   // 16B chunk (8 ci)
        const short8 af = *reinterpret_cast<const short8*>(wp + s * 16);
        const int xcd = col + dx;
        const int xx  = (xcd == 0) ? 36 : (xcd - 1);   // left halo remap
        {
            const int slot = (w + dy) * SPR + xx;
            const short8 bf = lds[c * CH_STRIDE + swz(slot)];
            acc0 = __builtin_amdgcn_mfma_f32_32x32x16_bf16(af, bf, acc0, 0, 0, 0);
        }
        {
            const int slot = (w + 8 + dy) * SPR + xx;
            const short8 bf = lds[c * CH_STRIDE + swz(slot)];
            acc1 = __builtin_amdgcn_mfma_f32_32x32x16_bf16(af, bf, acc1, 0, 0, 0);
        }
    }

    // C/D layout (verified m74/m101): col = lane&31, row = (reg&3)+8*(reg>>2)+4*half
    {
        const int gy = y0 + w;
        float* op = out + (size_t)(b * COUT) * HW + (size_t)gy * WW + x0 + col;
        #pragma unroll
        for (int reg = 0; reg < 16; ++reg) {
            const int oc_o = (reg & 3) + 8 * (reg >> 2) + 4 * half;
            __builtin_nontemporal_store(acc0[reg], op + (size_t)oc_o * HW);
        }
    }
    {
        const int gy = y0 + w + 8;
        float* op = out + (size_t)(b * COUT) * HW + (size_t)gy * WW + x0 + col;
        #pragma unroll
        for (int reg = 0; reg < 16; ++reg) {
            const int oc_o = (reg & 3) + 8 * (reg >> 2) + 4 * half;
            __builtin_nontemporal_store(acc1[reg], op + (size_t)oc_o * HW);
        }
    }
}

// ---------------------------------------------------------------------------
extern "C" void kernel_launch(void* const* d_in, const int* in_sizes, int n_in,
                              void* d_out, int out_size, void* d_ws, size_t ws_size,
                              hipStream_t stream) {
    const float* fmap       = (const float*)d_in[0];
    const float* mod        = (const float*)d_in[1];
    const float* kernel_mod = (const float*)d_in[2];
    const float* weights    = (const float*)d_in[3];
    float* out = (float*)d_out;
    unsigned short* wtb = (unsigned short*)d_ws;   // [8][32][288] bf16 = 147,456 B

    prep_weights<<<dim3(BATCH * COUT), dim3(320), 0, stream>>>(
        mod, kernel_mod, weights, wtb);

    conv_fused<<<dim3((WW / XW) * (HH / ROWS) * BATCH), dim3(512), 0, stream>>>(
        fmap, wtb, out);
}

// Round 13
// 114.859 us; speedup vs baseline: 1.0846x; 1.0846x over previous
//
#include <hip/hip_runtime.h>
#include <hip/hip_bf16.h>

#define BATCH 8
#define CIN 32
#define COUT 32
#define NK 4
#define HH 512
#define WW 512
#define HW (HH*WW)
#define EPSV 1e-8f

typedef __attribute__((ext_vector_type(8))) short short8;   // bf16 MFMA frag (4 VGPR)
typedef __attribute__((ext_vector_type(16))) float f32x16;  // 32x32 accumulator

static __device__ __forceinline__ unsigned short to_bf16(float f) {
    __hip_bfloat16 h = __float2bfloat16(f);
    return *reinterpret_cast<unsigned short*>(&h);
}

// ---------------------------------------------------------------------------
// Kernel 1: mixed+modulated+demodulated weights -> bf16 wt[b][oc][k], k=tap*32+ci
// ---------------------------------------------------------------------------
__global__ __launch_bounds__(320) void prep_weights(
    const float* __restrict__ mod,         // [B, CIN]
    const float* __restrict__ kernel_mod,  // [B, NK]
    const float* __restrict__ weights,     // [NK, COUT, CIN, 3, 3]
    unsigned short* __restrict__ wtb)      // [B, COUT, 288] bf16
{
    const int b  = blockIdx.x / COUT;
    const int oc = blockIdx.x % COUT;
    const int t  = threadIdx.x;            // 0..319, active < 288

    const float k0 = kernel_mod[b * NK + 0];
    const float k1 = kernel_mod[b * NK + 1];
    const float k2 = kernel_mod[b * NK + 2];
    const float k3 = kernel_mod[b * NK + 3];
    const float mx = fmaxf(fmaxf(k0, k1), fmaxf(k2, k3));
    const float e0 = expf(k0 - mx), e1 = expf(k1 - mx);
    const float e2 = expf(k2 - mx), e3 = expf(k3 - mx);
    const float inv_s = 1.0f / (e0 + e1 + e2 + e3);
    const float a0 = e0 * inv_s, a1 = e1 * inv_s, a2 = e2 * inv_s, a3 = e3 * inv_s;

    float w = 0.0f;
    int i = 0, tap = 0;
    if (t < CIN * 9) {
        i   = t / 9;
        tap = t % 9;
        const int base = (oc * CIN + i) * 9 + tap;
        const int nstride = COUT * CIN * 9;
        w = a0 * weights[base]
          + a1 * weights[base + nstride]
          + a2 * weights[base + 2 * nstride]
          + a3 * weights[base + 3 * nstride];
        w *= (mod[b * CIN + i] + 1.0f);
    }

    float s = w * w;
    #pragma unroll
    for (int off = 1; off < 64; off <<= 1) s += __shfl_xor(s, off);
    __shared__ float red[5];
    const int wid = t >> 6, lane = t & 63;
    if (lane == 0) red[wid] = s;
    __syncthreads();
    const float tot = red[0] + red[1] + red[2] + red[3] + red[4];
    const float inv_norm = rsqrtf(fmaxf(tot, EPSV));

    if (t < CIN * 9)
        wtb[(b * COUT + oc) * 288 + tap * CIN + i] = to_bf16(w * inv_norm);
}

// ---------------------------------------------------------------------------
// Kernel 2 (fused v7 = v2 structure widened to a 64x16 tile, NO setprio).
// Block: 512 thr (8 waves), tile 16 rows x 64 px, one batch slice.
// Staging (v2 scheme, 20 units): lane-pair float4 loads (2 dense segments
// per instr), direct 2B scatter into interleaved LDS [chunk(8ci)][slot][16B],
// quad-local swizzle. Slots r*69 + 0..67 = gx x0..x0+67 (17 quads);
// slot r*69+68 = left halo gx=x0-1.
// Compute: wave w -> 4 sub-tiles {row w, w+8} x {x-half 0, 32}; 18 MFMA each
// (72 total), NAMED accumulators (no arrays). launch_bounds(512,4): VGPR cap
// 128 (2 blocks/CU is LDS-bound anyway at 79.6KB).
// LEDGER (do not reintroduce): setprio = 4x regression (r6/r7/r10);
// reg-ARRAY batching = scratch spill (r6); depth-2 named rotation = no-op
// + overhead (r12); operand-swap epilogue = 32B segments (r9).
// ---------------------------------------------------------------------------
#define ROWS 16
#define XW 64
#define SR 18              // staged rows
#define SPR 69             // slots per row: 68 quad px + 1 left-halo
#define CH_STRIDE 1244     // padded chunk stride (max swz image 1243)
#define QP2 320            // padded quads per ci (306 real = 18 rows x 17)

static __device__ __forceinline__ int swz(int s) {
    return (s & ~3) | ((s ^ (s >> 2)) & 3);   // involution within quad groups
}

__global__ __launch_bounds__(512, 4) void conv_fused(
    const float* __restrict__ fmap,           // [B, CIN, H, W] f32
    const unsigned short* __restrict__ wtb,   // [B, COUT, 288] bf16
    float* __restrict__ out)                  // [B, COUT, H, W] f32
{
    __shared__ short8 lds[4 * CH_STRIDE];     // 79,616 B -> 2 blocks/CU

    // XCD-pinned decomposition: XCD (n&7) owns batch b, sweeps tiles row-major
    const int n  = blockIdx.x;
    const int b  = n & 7;
    const int m  = n >> 3;                    // 0..255
    const int x0 = (m & 7) * XW;              // 8 x-tiles
    const int y0 = (m >> 3) * ROWS;           // 32 y-tiles

    const int t    = threadIdx.x;
    const int lane = t & 63;
    const int w    = t >> 6;                  // wave 0..7
    const int oc   = lane & 31;
    const int half = lane >> 5;

    unsigned short* ldsu = (unsigned short*)lds;
    const float* fb = fmap + (size_t)b * CIN * HW;

    // ---- P1: dense quad staging (32 ci x 306 quads), v2 single-depth form ----
    #pragma unroll
    for (int k = 0; k < 20; ++k) {
        const int u  = t + 512 * k;           // < 10240 = 32*QP2, exact
        const int pr = u >> 1;                // lane-pair id
        const int cp = pr / QP2;              // ci-pair 0..15
        const int q  = pr - cp * QP2;         // 0..319
        const int ci = cp * 2 + (u & 1);
        if (q < 306) {
            const int r  = q / 17;            // 0..17
            const int qq = q - r * 17;        // 0..16
            const int gy = y0 + r - 1;
            const int gx = x0 + qq * 4;       // 16B-aligned (x0 % 64 == 0)
            float4 v = make_float4(0.f, 0.f, 0.f, 0.f);
            if (gy >= 0 && gy < HH && gx + 3 < WW)
                v = *reinterpret_cast<const float4*>(
                        fb + (size_t)ci * HW + (size_t)gy * WW + gx);
            const int c = ci >> 3, o = ci & 7;
            const int s0 = r * SPR + qq * 4;
            ldsu[(c * CH_STRIDE + swz(s0 + 0)) * 8 + o] = to_bf16(v.x);
            ldsu[(c * CH_STRIDE + swz(s0 + 1)) * 8 + o] = to_bf16(v.y);
            ldsu[(c * CH_STRIDE + swz(s0 + 2)) * 8 + o] = to_bf16(v.z);
            ldsu[(c * CH_STRIDE + swz(s0 + 3)) * 8 + o] = to_bf16(v.w);
        }
    }
    // ---- P1b: left halo column (gx = x0-1) -> slot 68 per row ----
    #pragma unroll
    for (int k = 0; k < 2; ++k) {
        const int e = t + 512 * k;
        if (e < 576) {                        // 32 ci x 18 rows
            const int ci = e & 31;
            const int r  = e >> 5;
            const int gy = y0 + r - 1;
            float f = 0.0f;
            if (gy >= 0 && gy < HH && x0 > 0)
                f = fb[(size_t)ci * HW + (size_t)gy * WW + (x0 - 1)];
            const int c = ci >> 3, o = ci & 7;
            ldsu[(c * CH_STRIDE + swz(r * SPR + 68)) * 8 + o] = to_bf16(f);
        }
    }
    __syncthreads();

    // ---- compute: wave w -> {row w, w+8} x {x-half 0, 32} ----
    const unsigned short* wp = wtb + (size_t)(b * COUT + oc) * 288 + half * 8;
    const int col = oc;                       // x within x-half

    f32x16 accA0, accA1, accB0, accB1;        // A=row w, B=row w+8; 0/1=x-half
    #pragma unroll
    for (int reg = 0; reg < 16; ++reg) {
        accA0[reg] = 0.0f; accA1[reg] = 0.0f;
        accB0[reg] = 0.0f; accB1[reg] = 0.0f;
    }

    #pragma unroll
    for (int s = 0; s < 18; ++s) {
        const int tap = s >> 1;               // 0..8
        const int dy  = tap / 3;
        const int dx  = tap % 3;
        const int c   = ((s & 1) << 1) | half;   // 16B chunk (8 ci)
        const short8 af = *reinterpret_cast<const short8*>(wp + s * 16);
        const int xiA = col + dx;             // 0..33  (gx = x0+xiA-1)
        const int sxA = (xiA == 0) ? 68 : (xiA - 1);   // left halo remap
        const int sxB = 31 + col + dx;        // xi 32..65, never halo
        const int rowA = (w + dy) * SPR;
        const int rowB = (w + 8 + dy) * SPR;
        {
            const short8 bf = lds[c * CH_STRIDE + swz(rowA + sxA)];
            accA0 = __builtin_amdgcn_mfma_f32_32x32x16_bf16(af, bf, accA0, 0, 0, 0);
        }
        {
            const short8 bf = lds[c * CH_STRIDE + swz(rowA + sxB)];
            accA1 = __builtin_amdgcn_mfma_f32_32x32x16_bf16(af, bf, accA1, 0, 0, 0);
        }
        {
            const short8 bf = lds[c * CH_STRIDE + swz(rowB + sxA)];
            accB0 = __builtin_amdgcn_mfma_f32_32x32x16_bf16(af, bf, accB0, 0, 0, 0);
        }
        {
            const short8 bf = lds[c * CH_STRIDE + swz(rowB + sxB)];
            accB1 = __builtin_amdgcn_mfma_f32_32x32x16_bf16(af, bf, accB1, 0, 0, 0);
        }
    }

    // C/D layout (verified m74/m101): col = lane&31, row = (reg&3)+8*(reg>>2)+4*half
    {
        const int gy = y0 + w;
        float* op = out + (size_t)(b * COUT) * HW + (size_t)gy * WW + x0 + col;
        #pragma unroll
        for (int reg = 0; reg < 16; ++reg) {
            const int oc_o = (reg & 3) + 8 * (reg >> 2) + 4 * half;
            __builtin_nontemporal_store(accA0[reg], op + (size_t)oc_o * HW);
            __builtin_nontemporal_store(accA1[reg], op + (size_t)oc_o * HW + 32);
        }
    }
    {
        const int gy = y0 + w + 8;
        float* op = out + (size_t)(b * COUT) * HW + (size_t)gy * WW + x0 + col;
        #pragma unroll
        for (int reg = 0; reg < 16; ++reg) {
            const int oc_o = (reg & 3) + 8 * (reg >> 2) + 4 * half;
            __builtin_nontemporal_store(accB0[reg], op + (size_t)oc_o * HW);
            __builtin_nontemporal_store(accB1[reg], op + (size_t)oc_o * HW + 32);
        }
    }
}

// ---------------------------------------------------------------------------
extern "C" void kernel_launch(void* const* d_in, const int* in_sizes, int n_in,
                              void* d_out, int out_size, void* d_ws, size_t ws_size,
                              hipStream_t stream) {
    const float* fmap       = (const float*)d_in[0];
    const float* mod        = (const float*)d_in[1];
    const float* kernel_mod = (const float*)d_in[2];
    const float* weights    = (const float*)d_in[3];
    float* out = (float*)d_out;
    unsigned short* wtb = (unsigned short*)d_ws;   // [8][32][288] bf16 = 147,456 B

    prep_weights<<<dim3(BATCH * COUT), dim3(320), 0, stream>>>(
        mod, kernel_mod, weights, wtb);

    conv_fused<<<dim3((WW / XW) * (HH / ROWS) * BATCH), dim3(512), 0, stream>>>(
        fmap, wtb, out);
}